// Round 4
// baseline (671.933 us; speedup 1.0000x reference)
//
#include <hip/hip_runtime.h>
#include <stdint.h>

#define TKN 2048
#define DM 512
#define NP 32
#define HF 2048
#define NHD 8
#define SEQ 1024
#define MAXROWS 10240
#define MTMAX (MAXROWS/64)

typedef __attribute__((ext_vector_type(8))) __bf16 bf16x8;
typedef __attribute__((ext_vector_type(4))) float f32x4;

__device__ __forceinline__ unsigned short bfr(float x){
  unsigned u = __float_as_uint(x);
  u += 0x7FFFu + ((u>>16)&1u);
  return (unsigned short)(u>>16);
}
__device__ __forceinline__ unsigned bf2(float lo, float hi){
  return (unsigned)bfr(lo) | ((unsigned)bfr(hi)<<16);
}

// ---------------- router: logits + top4 + counts ----------------
__global__ __launch_bounds__(256) void router_kernel(
    const float* __restrict__ x, const float* __restrict__ Wr, const float* __restrict__ br,
    int* __restrict__ idx, int* __restrict__ counts)
{
  __shared__ float xr[DM];
  __shared__ float lg[NP];
  const int t = blockIdx.x, tid = threadIdx.x;
  *(float2*)&xr[tid*2] = *(const float2*)&x[(size_t)t*DM + tid*2];
  __syncthreads();
  const int n = tid>>3, j = tid&7;
  float p = 0.f;
  const float4* xr4 = (const float4*)xr;
  #pragma unroll 4
  for (int m=0;m<16;++m){
    float4 wv = *(const float4*)&Wr[(size_t)n*DM + m*32 + j*4];
    float4 xv = xr4[m*8 + j];
    p += wv.x*xv.x + wv.y*xv.y + wv.z*xv.z + wv.w*xv.w;
  }
  p += __shfl_xor(p,1); p += __shfl_xor(p,2); p += __shfl_xor(p,4);
  if (j==0) lg[n] = p + br[n];
  __syncthreads();
  if (tid==0){
    unsigned chosen=0;
    #pragma unroll
    for (int k=0;k<4;++k){
      float best=-1e30f; int bi=0;
      for (int i=0;i<NP;++i){
        if (((chosen>>i)&1u)==0 && lg[i]>best){ best=lg[i]; bi=i; }
      }
      chosen |= (1u<<bi);
      idx[t*4+k]=bi;
      atomicAdd(&counts[bi],1);
    }
  }
}

// ---------------- scan: tile-aligned bases + tile->neuron map ----------------
__global__ void scan_kernel(const int* __restrict__ counts, int* __restrict__ rowbase,
                            int* __restrict__ tile2n)
{
  if (threadIdx.x==0 && blockIdx.x==0){
    int t=0, rb=0;
    for (int n=0;n<NP;++n){
      rowbase[n]=rb;
      int c=counts[n];
      int tiles=(c+63)>>6;
      for (int i=0;i<tiles;++i) tile2n[t++]=n;
      rb += tiles<<6;
    }
    for (; t<MTMAX; ++t) tile2n[t]=-1;
  }
}

// ---------------- fill: rowinfo[row] = t*4+k ----------------
__global__ void fill_kernel(const int* __restrict__ idx, const int* __restrict__ rowbase,
                            int* __restrict__ fillp, unsigned* __restrict__ rowinfo)
{
  int t = blockIdx.x*256 + threadIdx.x;
  if (t >= TKN) return;
  #pragma unroll
  for (int k=0;k<4;++k){
    int n = idx[t*4+k];
    int pos = atomicAdd(&fillp[n],1);
    rowinfo[rowbase[n]+pos] = (unsigned)(t*4+k);
  }
}

// ---------------- gather: Xg[row] = bf16(x[token]) (zeros for pad rows) ----------------
__global__ __launch_bounds__(256) void gather_kernel(
    const float* __restrict__ x, const unsigned* __restrict__ rowinfo,
    unsigned short* __restrict__ Xg)
{
  int g = blockIdx.x*256 + threadIdx.x;   // MAXROWS*64 chunks of 8
  int row = g>>6, c8 = (g&63)<<3;
  unsigned info = rowinfo[row];
  uint4 outv;
  if (info==0xFFFFFFFFu){ outv.x=0;outv.y=0;outv.z=0;outv.w=0; }
  else {
    int t = (int)(info>>2);
    float4 a = *(const float4*)&x[(size_t)t*DM + c8];
    float4 b = *(const float4*)&x[(size_t)t*DM + c8 + 4];
    outv.x=bf2(a.x,a.y); outv.y=bf2(a.z,a.w); outv.z=bf2(b.x,b.y); outv.w=bf2(b.z,b.w);
  }
  *(uint4*)&Xg[(size_t)row*DM + c8] = outv;
}

// ---------------- grouped FFN GEMMs ----
// PHASE 1: Hg = gelu(Xg @ W1[n] + b1[n])   (Kd=512, Nc=2048, out bf16)
// PHASE 2: nf32[token] += 0.25*(Hg @ W2[n] + b2[n])  (Kd=2048, Nc=512, atomic k-mean)
template<int PHASE>
__global__ __launch_bounds__(256) void ffn_gemm(
    const unsigned short* __restrict__ A, const float* __restrict__ W,
    const float* __restrict__ bias, unsigned short* __restrict__ Hg,
    float* __restrict__ nf32, const int* __restrict__ tile2n,
    const unsigned* __restrict__ rowinfo)
{
  constexpr int Kd = (PHASE==1)? DM : HF;
  constexpr int Nc = (PHASE==1)? HF : DM;
  const int n = tile2n[blockIdx.y];
  if (n < 0) return;
  const int r0 = blockIdx.y*64;
  const int c0 = blockIdx.x*64;
  const int tid = threadIdx.x;
  const int w = tid>>6, l = tid&63;
  const int wm = w>>1, wn = w&1;
  __shared__ unsigned short Al[64][40];
  __shared__ unsigned short Bl[64][40];
  f32x4 acc[2][2] = {};
  const unsigned short* Arow = A + (size_t)r0*Kd;
  const float* Wn = W + (size_t)n*Kd*Nc;
  const int ar = tid>>2, ac8 = (tid&3)*8;
  const int bk = tid>>4, bc4 = (tid&15)*4;

  for (int k0=0; k0<Kd; k0+=32){
    *(uint4*)&Al[ar][ac8] = *(const uint4*)&Arow[(size_t)ar*Kd + k0 + ac8];
    #pragma unroll
    for (int kk=bk; kk<32; kk+=16){
      float4 wv = *(const float4*)&Wn[(size_t)(k0+kk)*Nc + c0 + bc4];
      Bl[bc4+0][kk]=bfr(wv.x); Bl[bc4+1][kk]=bfr(wv.y);
      Bl[bc4+2][kk]=bfr(wv.z); Bl[bc4+3][kk]=bfr(wv.w);
    }
    __syncthreads();
    bf16x8 a0 = *reinterpret_cast<const bf16x8*>(&Al[wm*32 + (l&15)][(l>>4)*8]);
    bf16x8 a1 = *reinterpret_cast<const bf16x8*>(&Al[wm*32 + 16 + (l&15)][(l>>4)*8]);
    bf16x8 b0 = *reinterpret_cast<const bf16x8*>(&Bl[wn*32 + (l&15)][(l>>4)*8]);
    bf16x8 b1v= *reinterpret_cast<const bf16x8*>(&Bl[wn*32 + 16 + (l&15)][(l>>4)*8]);
    acc[0][0] = __builtin_amdgcn_mfma_f32_16x16x32_bf16(a0,b0, acc[0][0],0,0,0);
    acc[0][1] = __builtin_amdgcn_mfma_f32_16x16x32_bf16(a0,b1v,acc[0][1],0,0,0);
    acc[1][0] = __builtin_amdgcn_mfma_f32_16x16x32_bf16(a1,b0, acc[1][0],0,0,0);
    acc[1][1] = __builtin_amdgcn_mfma_f32_16x16x32_bf16(a1,b1v,acc[1][1],0,0,0);
    __syncthreads();
  }

  #pragma unroll
  for (int mf=0; mf<2; ++mf)
  #pragma unroll
  for (int nf=0; nf<2; ++nf){
    int col = c0 + wn*32 + nf*16 + (l&15);
    #pragma unroll
    for (int r=0; r<4; ++r){
      int row = r0 + wm*32 + mf*16 + (l>>4)*4 + r;
      float v = acc[mf][nf][r] + bias[n*Nc + col];
      if (PHASE==1){
        float y = 0.7978845608028654f*(v + 0.044715f*v*v*v);
        float e2 = __expf(2.f*y);
        float t  = 1.f - 2.f/(e2+1.f);
        Hg[(size_t)row*HF + col] = bfr(0.5f*v*(1.f+t));
      } else {
        unsigned info = rowinfo[row];
        if (info != 0xFFFFFFFFu){
          int tok = (int)(info>>2);
          atomicAdd(&nf32[(size_t)tok*DM + col], 0.25f*v);
        }
      }
    }
  }
}

// ---------------- cvt: nbf = bf16(nf32) ----------------
__global__ __launch_bounds__(256) void cvt_kernel(
    const float* __restrict__ nf32, unsigned short* __restrict__ nbf)
{
  int g = blockIdx.x*256 + threadIdx.x;   // TKN*DM/4 float4s
  float4 v = ((const float4*)nf32)[g];
  uint2 u; u.x=bf2(v.x,v.y); u.y=bf2(v.z,v.w);
  ((uint2*)nbf)[g] = u;
}

// ---------------- projection GEMM (NT: W is [Nc][512] row-major f32) ----------------
template<int OUTBF>
__global__ __launch_bounds__(256) void proj_gemm(
    const unsigned short* __restrict__ A, const float* __restrict__ W,
    const float* __restrict__ bias, unsigned short* __restrict__ outb,
    float* __restrict__ outf, int Nc)
{
  const int r0 = blockIdx.y*64, c0 = blockIdx.x*64;
  const int tid = threadIdx.x;
  const int w = tid>>6, l = tid&63;
  const int wm = w>>1, wn = w&1;
  __shared__ unsigned short Al[64][40];
  __shared__ unsigned short Bl[64][40];
  f32x4 acc[2][2] = {};
  const unsigned short* Arow = A + (size_t)r0*DM;
  const int ar = tid>>2, ac8 = (tid&3)*8;
  const int bc = tid>>2, bk8 = (tid&3)*8;

  for (int k0=0; k0<DM; k0+=32){
    *(uint4*)&Al[ar][ac8] = *(const uint4*)&Arow[(size_t)ar*DM + k0 + ac8];
    float4 w0 = *(const float4*)&W[(size_t)(c0+bc)*DM + k0 + bk8];
    float4 w1 = *(const float4*)&W[(size_t)(c0+bc)*DM + k0 + bk8 + 4];
    uint4 pk; pk.x=bf2(w0.x,w0.y); pk.y=bf2(w0.z,w0.w); pk.z=bf2(w1.x,w1.y); pk.w=bf2(w1.z,w1.w);
    *(uint4*)&Bl[bc][bk8] = pk;
    __syncthreads();
    bf16x8 a0 = *reinterpret_cast<const bf16x8*>(&Al[wm*32 + (l&15)][(l>>4)*8]);
    bf16x8 a1 = *reinterpret_cast<const bf16x8*>(&Al[wm*32 + 16 + (l&15)][(l>>4)*8]);
    bf16x8 b0 = *reinterpret_cast<const bf16x8*>(&Bl[wn*32 + (l&15)][(l>>4)*8]);
    bf16x8 b1v= *reinterpret_cast<const bf16x8*>(&Bl[wn*32 + 16 + (l&15)][(l>>4)*8]);
    acc[0][0] = __builtin_amdgcn_mfma_f32_16x16x32_bf16(a0,b0, acc[0][0],0,0,0);
    acc[0][1] = __builtin_amdgcn_mfma_f32_16x16x32_bf16(a0,b1v,acc[0][1],0,0,0);
    acc[1][0] = __builtin_amdgcn_mfma_f32_16x16x32_bf16(a1,b0, acc[1][0],0,0,0);
    acc[1][1] = __builtin_amdgcn_mfma_f32_16x16x32_bf16(a1,b1v,acc[1][1],0,0,0);
    __syncthreads();
  }

  #pragma unroll
  for (int mf=0; mf<2; ++mf)
  #pragma unroll
  for (int nf=0; nf<2; ++nf){
    int col = c0 + wn*32 + nf*16 + (l&15);
    #pragma unroll
    for (int r=0; r<4; ++r){
      int row = r0 + wm*32 + mf*16 + (l>>4)*4 + r;
      float v = acc[mf][nf][r] + bias[col];
      if (OUTBF) outb[(size_t)row*Nc + col] = bfr(v);
      else       outf[(size_t)row*Nc + col] = v;
    }
  }
}

// ---------------- fused attention (flash-style, 64 q rows / block) ----------------
__global__ __launch_bounds__(256) void attn_kernel(
    const unsigned short* __restrict__ qkv, unsigned short* __restrict__ obuf)
{
  const int qt = blockIdx.x;       // 16 q-tiles
  const int bh = blockIdx.y;       // 16 (b,h)
  const int b = bh>>3, h = bh&7;
  const int tid = threadIdx.x, w = tid>>6, l = tid&63;
  __shared__ unsigned short Kl[64][72];
  __shared__ unsigned short Vt[64][72];
  __shared__ unsigned short Pw[4][16][80];

  const int qrow = b*SEQ + qt*64 + w*16 + (l&15);
  bf16x8 aq[2];
  #pragma unroll
  for (int s=0;s<2;++s)
    aq[s] = *reinterpret_cast<const bf16x8*>(&qkv[(size_t)qrow*1536 + h*64 + s*32 + (l>>4)*8]);

  f32x4 oacc[4] = {};
  float m_prev[4], l_run[4];
  #pragma unroll
  for (int r=0;r<4;++r){ m_prev[r]=-1e30f; l_run[r]=0.f; }

  for (int kv0=0; kv0<SEQ; kv0+=64){
    __syncthreads();
    #pragma unroll
    for (int it=0; it<2; ++it){
      int q = tid + it*256;
      int kv = q>>3, d8 = (q&7)*8;
      const unsigned short* src = &qkv[(size_t)(b*SEQ + kv0 + kv)*1536 + DM + h*64 + d8];
      *(uint4*)&Kl[kv][d8] = *(const uint4*)src;
      uint4 vv = *(const uint4*)(src + DM);
      const unsigned short* ve = (const unsigned short*)&vv;
      #pragma unroll
      for (int j=0;j<8;++j) Vt[d8+j][kv] = ve[j];
    }
    __syncthreads();

    f32x4 sacc[4] = {};
    #pragma unroll
    for (int s=0;s<2;++s){
      #pragma unroll
      for (int nf=0;nf<4;++nf){
        bf16x8 bk = *reinterpret_cast<const bf16x8*>(&Kl[nf*16 + (l&15)][s*32 + (l>>4)*8]);
        sacc[nf] = __builtin_amdgcn_mfma_f32_16x16x32_bf16(aq[s], bk, sacc[nf],0,0,0);
      }
    }
    #pragma unroll
    for (int r=0;r<4;++r){
      float mx = -1e30f;
      #pragma unroll
      for (int nf=0;nf<4;++nf){ sacc[nf][r] *= 0.125f; mx = fmaxf(mx, sacc[nf][r]); }
      #pragma unroll
      for (int d=1; d<16; d<<=1) mx = fmaxf(mx, __shfl_xor(mx, d));
      float mn = fmaxf(m_prev[r], mx);
      float alpha = __expf(m_prev[r] - mn);
      float rs = 0.f;
      #pragma unroll
      for (int nf=0;nf<4;++nf){
        float pv = __expf(sacc[nf][r] - mn);
        sacc[nf][r] = pv; rs += pv;
      }
      #pragma unroll
      for (int d=1; d<16; d<<=1) rs += __shfl_xor(rs, d);
      l_run[r] = l_run[r]*alpha + rs;
      m_prev[r] = mn;
      #pragma unroll
      for (int nf=0;nf<4;++nf) oacc[nf][r] *= alpha;
      int prow = (l>>4)*4 + r;
      #pragma unroll
      for (int nf=0;nf<4;++nf) Pw[w][prow][(l&15)+nf*16] = bfr(sacc[nf][r]);
    }
    __syncthreads();   // defensive: ensure Pw writes drained before PV fragment reads
    #pragma unroll
    for (int s=0;s<2;++s){
      bf16x8 ap = *reinterpret_cast<const bf16x8*>(&Pw[w][l&15][s*32 + (l>>4)*8]);
      #pragma unroll
      for (int nf=0;nf<4;++nf){
        bf16x8 bv = *reinterpret_cast<const bf16x8*>(&Vt[nf*16 + (l&15)][s*32 + (l>>4)*8]);
        oacc[nf] = __builtin_amdgcn_mfma_f32_16x16x32_bf16(ap, bv, oacc[nf],0,0,0);
      }
    }
  }

  #pragma unroll
  for (int r=0;r<4;++r){
    float inv = 1.f/l_run[r];
    int row = b*SEQ + qt*64 + w*16 + (l>>4)*4 + r;
    #pragma unroll
    for (int nf=0;nf<4;++nf)
      obuf[(size_t)row*DM + h*64 + nf*16 + (l&15)] = bfr(oacc[nf][r]*inv);
  }
}

// ---------------- fused dual LayerNorm ----------------
__global__ __launch_bounds__(256) void ln_kernel(
    const float* __restrict__ x, const float* __restrict__ attn, const float* __restrict__ nout,
    const float* __restrict__ w1, const float* __restrict__ b1,
    const float* __restrict__ w2, const float* __restrict__ b2, float* __restrict__ out)
{
  __shared__ float red[8];
  const int row = blockIdx.x, tid = threadIdx.x;
  const size_t base = (size_t)row*DM;
  const int d0 = tid, d1 = tid+256;
  float v0 = x[base+d0] + attn[base+d0];
  float v1 = x[base+d1] + attn[base+d1];
  float s = v0+v1, q = v0*v0+v1*v1;
  #pragma unroll
  for (int d=32; d; d>>=1){ s += __shfl_xor(s,d); q += __shfl_xor(q,d); }
  if ((tid&63)==0){ red[tid>>6]=s; red[4+(tid>>6)]=q; }
  __syncthreads();
  s = red[0]+red[1]+red[2]+red[3];
  q = red[4]+red[5]+red[6]+red[7];
  float mean = s*(1.f/DM), var = q*(1.f/DM) - mean*mean;
  float rstd = rsqrtf(var + 1e-5f);
  float u0 = (v0-mean)*rstd*w1[d0] + b1[d0] + nout[base+d0];
  float u1 = (v1-mean)*rstd*w1[d1] + b1[d1] + nout[base+d1];
  s = u0+u1; q = u0*u0+u1*u1;
  #pragma unroll
  for (int d=32; d; d>>=1){ s += __shfl_xor(s,d); q += __shfl_xor(q,d); }
  __syncthreads();
  if ((tid&63)==0){ red[tid>>6]=s; red[4+(tid>>6)]=q; }
  __syncthreads();
  s = red[0]+red[1]+red[2]+red[3];
  q = red[4]+red[5]+red[6]+red[7];
  float mean2 = s*(1.f/DM), var2 = q*(1.f/DM) - mean2*mean2;
  float rstd2 = rsqrtf(var2 + 1e-5f);
  out[base+d0] = (u0-mean2)*rstd2*w2[d0] + b2[d0];
  out[base+d1] = (u1-mean2)*rstd2*w2[d1] + b2[d1];
}

extern "C" void kernel_launch(void* const* d_in, const int* in_sizes, int n_in,
                              void* d_out, int out_size, void* d_ws, size_t ws_size,
                              hipStream_t stream)
{
  const float* x    = (const float*)d_in[0];
  const float* Wr   = (const float*)d_in[1];
  const float* br   = (const float*)d_in[2];
  const float* W1   = (const float*)d_in[3];
  const float* b1   = (const float*)d_in[4];
  const float* W2   = (const float*)d_in[5];
  const float* b2   = (const float*)d_in[6];
  const float* Wqkv = (const float*)d_in[7];
  const float* bqkv = (const float*)d_in[8];
  const float* Wo   = (const float*)d_in[9];
  const float* bo   = (const float*)d_in[10];
  const float* ln1w = (const float*)d_in[11];
  const float* ln1b = (const float*)d_in[12];
  const float* ln2w = (const float*)d_in[13];
  const float* ln2b = (const float*)d_in[14];
  float* out = (float*)d_out;

  // ---- workspace layout (total 52,559,872 B ≈ 50.1 MB, tight live-range aliasing) ----
  char* p = (char*)d_ws;
  int* counts  = (int*)p;              // 32 ints
  int* fillp   = (int*)(p+128);        // 32 ints
  int* rowbase = (int*)(p+256);        // 32 ints
  int* tile2n  = (int*)(p+512);        // 160 ints
  int* idx     = (int*)(p+2048);       // 8192 ints (ends 34816)
  unsigned* rowinfo = (unsigned*)(p+36864); // 10240 u32 (ends 77824)
  // region A: Xg [131072, 10616832) — dead after ffn_gemm<1>
  unsigned short* Xg  = (unsigned short*)(p+131072);
  float*          nf32 = (float*)(p+131072);                 // alias A (4,194,304 B)
  unsigned short* nbf  = (unsigned short*)(p+131072+4194304); // alias A (2,097,152 B)
  // region B: Hg [10616832, 52559872) — dead after ffn_gemm<2>
  unsigned short* Hg   = (unsigned short*)(p+10616832);
  unsigned short* qkvb = (unsigned short*)(p+10616832);            // alias B (6,291,456 B)
  unsigned short* obuf = (unsigned short*)(p+10616832+6291456);    // alias B (2,097,152 B)
  float*          attn = (float*)(p+10616832+6291456+2097152);     // alias B (4,194,304 B)

  hipMemsetAsync(counts, 0, 256, stream);                 // counts + fillp
  hipMemsetAsync(rowinfo, 0xFF, MAXROWS*sizeof(unsigned), stream);

  router_kernel<<<TKN, 256, 0, stream>>>(x, Wr, br, idx, counts);
  scan_kernel<<<1, 64, 0, stream>>>(counts, rowbase, tile2n);
  fill_kernel<<<TKN/256, 256, 0, stream>>>(idx, rowbase, fillp, rowinfo);
  gather_kernel<<<MAXROWS*64/256, 256, 0, stream>>>(x, rowinfo, Xg);
  ffn_gemm<1><<<dim3(HF/64, MTMAX), 256, 0, stream>>>(Xg, W1, b1, Hg, nullptr, tile2n, rowinfo);
  // Xg now dead -> zero nf32 (aliases Xg) for the atomic k-mean accumulate
  hipMemsetAsync(nf32, 0, (size_t)TKN*DM*4, stream);
  ffn_gemm<2><<<dim3(DM/64, MTMAX), 256, 0, stream>>>(Hg, W2, b2, nullptr, nf32, tile2n, rowinfo);
  cvt_kernel<<<TKN*DM/4/256, 256, 0, stream>>>(nf32, nbf);
  // Hg now dead -> qkvb/obuf/attn live in its region
  proj_gemm<1><<<dim3(1536/64, TKN/64), 256, 0, stream>>>(nbf, Wqkv, bqkv, qkvb, nullptr, 1536);
  attn_kernel<<<dim3(16,16), 256, 0, stream>>>(qkvb, obuf);
  proj_gemm<0><<<dim3(DM/64, TKN/64), 256, 0, stream>>>(obuf, Wo, bo, nullptr, attn, DM);
  ln_kernel<<<TKN, 256, 0, stream>>>(x, attn, nf32, ln1w, ln1b, ln2w, ln2b, out);
}